// Round 1
// baseline (351.340 us; speedup 1.0000x reference)
//
#include <hip/hip_runtime.h>
#include <math.h>

static constexpr int BROWS   = 16384;
static constexpr int NC      = 784;
static constexpr int TR      = 16;     // rows staged per block (16*784*4B = 50 KiB LDS -> 3 blocks/CU)
static constexpr int THREADS = 256;
static constexpr float EPS   = 1e-5f;

__device__ __forceinline__ float gelu_exact(float x) {
    return 0.5f * x * (1.0f + erff(x * 0.7071067811865475f));
}

// One sparse layer: out[b,j] = act( sum_k in'[b, idx[j,k]] * W[j,k] + bias[j] )
// where in'[b,c] = AFFINE ? in[b,c]*scale[c]+shift[c] : in[b,c]   (fused BN apply)
// STATS: also accumulate per-column sum / sumsq of the activation (for the next BN).
template<int K, bool AFFINE, bool STATS, bool RELU>
__global__ __launch_bounds__(THREADS, 2)
void sparse_layer(const float* __restrict__ in,
                  const int*   __restrict__ idx,
                  const float* __restrict__ W,
                  const float* __restrict__ bias,
                  const float* __restrict__ scale,
                  const float* __restrict__ shift,
                  float*       __restrict__ out,
                  float*       __restrict__ ssum,
                  float*       __restrict__ ssq)
{
    __shared__ float rows[TR * NC];
    const int    tid  = threadIdx.x;
    const size_t row0 = (size_t)blockIdx.x * TR;

    // ---- Stage TR full rows into LDS (coalesced float4), fusing the BN affine ----
    {
        const float4* in4   = (const float4*)(in + row0 * NC);
        float4*       rows4 = (float4*)rows;
        const int     total4 = TR * NC / 4;          // 3136
        for (int i = tid; i < total4; i += THREADS) {
            float4 v = in4[i];
            if (AFFINE) {
                const int c4 = i % (NC / 4);         // column/4 (NC divisible by 4)
                const float4 sc = ((const float4*)scale)[c4];
                const float4 sh = ((const float4*)shift)[c4];
                v.x = fmaf(v.x, sc.x, sh.x);
                v.y = fmaf(v.y, sc.y, sh.y);
                v.z = fmaf(v.z, sc.z, sh.z);
                v.w = fmaf(v.w, sc.w, sh.w);
            }
            rows4[i] = v;
        }
    }
    __syncthreads();

    // ---- Compute: each thread owns columns j = tid, tid+256, ... across all TR rows ----
    for (int j = tid; j < NC; j += THREADS) {
        int   ji[K];
        float jw[K];
        #pragma unroll
        for (int k = 0; k < K; ++k) {
            ji[k] = idx[j * K + k];
            jw[k] = W[j * K + k];
        }
        const float jb = bias[j];
        float s1 = 0.0f, s2 = 0.0f;
        #pragma unroll 4
        for (int r = 0; r < TR; ++r) {
            float acc = jb;
            #pragma unroll
            for (int k = 0; k < K; ++k)
                acc = fmaf(rows[r * NC + ji[k]], jw[k], acc);
            const float u = RELU ? fmaxf(acc, 0.0f) : gelu_exact(acc);
            out[(row0 + r) * NC + j] = u;                 // coalesced: lanes have consecutive j
            if (STATS) { s1 += u; s2 = fmaf(u, u, s2); }
        }
        if (STATS) {                                      // one atomic per (block, column)
            atomicAdd(&ssum[j], s1);
            atomicAdd(&ssq[j],  s2);
        }
    }
}

__global__ void bn_finalize(const float* __restrict__ sum,
                            const float* __restrict__ sumsq,
                            const float* __restrict__ gamma,
                            const float* __restrict__ beta,
                            float* __restrict__ scale,
                            float* __restrict__ shift)
{
    const int j = blockIdx.x * blockDim.x + threadIdx.x;
    if (j < NC) {
        const float invB = 1.0f / (float)BROWS;
        const float m    = sum[j] * invB;
        const float var  = fmaf(-m, m, sumsq[j] * invB);  // E[x^2] - m^2 (biased)
        const float sc   = gamma[j] * rsqrtf(var + EPS);
        scale[j] = sc;
        shift[j] = fmaf(-m, sc, beta[j]);
    }
}

extern "C" void kernel_launch(void* const* d_in, const int* in_sizes, int n_in,
                              void* d_out, int out_size, void* d_ws, size_t ws_size,
                              hipStream_t stream)
{
    const float* x    = (const float*)d_in[0];
    const int*   idx1 = (const int*)  d_in[1];
    const float* W1   = (const float*)d_in[2];
    const float* b1   = (const float*)d_in[3];
    const int*   idx2 = (const int*)  d_in[4];
    const float* W2   = (const float*)d_in[5];
    const float* b2   = (const float*)d_in[6];
    const int*   idx3 = (const int*)  d_in[7];
    const float* W3   = (const float*)d_in[8];
    const float* b3   = (const float*)d_in[9];
    const float* g2   = (const float*)d_in[10];
    const float* be2  = (const float*)d_in[11];
    const float* g3   = (const float*)d_in[12];
    const float* be3  = (const float*)d_in[13];
    float* out = (float*)d_out;

    const size_t BN_ELEMS = (size_t)BROWS * NC;
    // Ping-pong: bufA = d_out (fully rewritten by the final layer; no read/write alias
    // on any launch: L1 w:A, L2 r:A w:B, L3 r:B w:A, L4 r:A w:B, L5 r:B w:out(=A slot ok,
    // but L5 only READS bufB)). bufB + stats live in the workspace.
    float* bufA  = out;
    float* bufB  = (float*)d_ws;
    float* stats = bufB + BN_ELEMS;
    float* sum2a = stats + 0*NC;  float* ssq2a = stats + 1*NC;
    float* sum3  = stats + 2*NC;  float* ssq3  = stats + 3*NC;
    float* sum2b = stats + 4*NC;  float* ssq2b = stats + 5*NC;
    float* sc2a  = stats + 6*NC;  float* sh2a  = stats + 7*NC;
    float* sc3   = stats + 8*NC;  float* sh3   = stats + 9*NC;
    float* sc2b  = stats + 10*NC; float* sh2b  = stats + 11*NC;

    // ws is re-poisoned to 0xAA before every launch: zero the accumulators.
    hipMemsetAsync(stats, 0, 6 * NC * sizeof(float), stream);

    const dim3 grid(BROWS / TR), blk(THREADS);
    const dim3 fgrid((NC + THREADS - 1) / THREADS);

    // L1: h1 = gelu(sp1(x))                       -> bufA
    sparse_layer<2,false,false,false><<<grid, blk, 0, stream>>>(
        x, idx1, W1, b1, nullptr, nullptr, bufA, nullptr, nullptr);
    // L2: u2 = gelu(sp2(h1)), bn2a stats          -> bufB
    sparse_layer<4,false,true,false><<<grid, blk, 0, stream>>>(
        bufA, idx2, W2, b2, nullptr, nullptr, bufB, sum2a, ssq2a);
    bn_finalize<<<fgrid, blk, 0, stream>>>(sum2a, ssq2a, g2, be2, sc2a, sh2a);
    // L3: u3 = gelu(sp3(bn2a(u2))), bn3 stats     -> bufA
    sparse_layer<8,true,true,false><<<grid, blk, 0, stream>>>(
        bufB, idx3, W3, b3, sc2a, sh2a, bufA, sum3, ssq3);
    bn_finalize<<<fgrid, blk, 0, stream>>>(sum3, ssq3, g3, be3, sc3, sh3);
    // L4: u4 = gelu(sp2(bn3(u3))), bn2b stats     -> bufB
    sparse_layer<4,true,true,false><<<grid, blk, 0, stream>>>(
        bufA, idx2, W2, b2, sc3, sh3, bufB, sum2b, ssq2b);
    bn_finalize<<<fgrid, blk, 0, stream>>>(sum2b, ssq2b, g2, be2, sc2b, sh2b);
    // L5: out = relu(sp1(bn2b(u4)))               -> d_out
    sparse_layer<2,true,false,true><<<grid, blk, 0, stream>>>(
        bufB, idx1, W1, b1, sc2b, sh2b, out, nullptr, nullptr);
}

// Round 2
// 263.169 us; speedup vs baseline: 1.3350x; 1.3350x over previous
//
#include <hip/hip_runtime.h>
#include <math.h>

static constexpr int BROWS   = 16384;
static constexpr int NC      = 784;
static constexpr int TR      = 8;      // rows/block: 8*784*4B = 25088 B LDS -> 6 blocks/CU, 24 waves/CU
static constexpr int THREADS = 256;
static constexpr int NREP    = 4;      // replicated stat accumulators (atomic contention)
static constexpr float EPS   = 1e-5f;

#if defined(__has_builtin)
#if __has_builtin(__builtin_amdgcn_global_load_lds)
#define HAVE_ASYNC_LDS 1
#endif
#endif

__device__ __forceinline__ void stage16(const float4* g, float4* l) {
#ifdef HAVE_ASYNC_LDS
    __builtin_amdgcn_global_load_lds(
        (const __attribute__((address_space(1))) void*)g,
        (__attribute__((address_space(3))) void*)l, 16, 0, 0);
#else
    *l = *g;
#endif
}

__device__ __forceinline__ float gelu_exact(float x) {
    return 0.5f * x * (1.0f + erff(x * 0.7071067811865475f));
}

// out[b,j] = act( sum_k in[b, idx[j,k]] * W[j,k] + bias[j] )
// (BN affine of the previous layer is pre-folded into W/bias on the host-side graph
//  by bn_fold, so staging is a pure async copy.)
template<int K, bool STATS, bool RELU>
__global__ __launch_bounds__(THREADS, 6)
void sparse_layer(const float* __restrict__ in,
                  const int*   __restrict__ idx,
                  const float* __restrict__ W,
                  const float* __restrict__ bias,
                  float*       __restrict__ out,
                  float*       __restrict__ ssum,
                  float*       __restrict__ ssq)
{
    __shared__ float rows[TR * NC];
    const int    tid  = threadIdx.x;
    const size_t row0 = (size_t)blockIdx.x * TR;

    // ---- Async-stage TR full rows into LDS (global_load_lds dwordx4) ----
    {
        const float4* in4   = (const float4*)(in + row0 * NC);
        float4*       rows4 = (float4*)rows;
        constexpr int TOTAL4 = TR * NC / 4;          // 1568
        for (int i = tid; i < TOTAL4; i += THREADS)
            stage16(in4 + i, rows4 + i);
    }
    __syncthreads();   // emits vmcnt(0) drain of the LDS-DMA before the barrier

    // ---- Each thread owns columns j = tid, tid+256, ... across all TR rows ----
    for (int j = tid; j < NC; j += THREADS) {
        int   ji[K];
        float jw[K];
        #pragma unroll
        for (int k = 0; k < K; ++k) {
            ji[k] = idx[j * K + k];
            jw[k] = W[j * K + k];
        }
        const float jb = bias[j];
        float s1 = 0.0f, s2 = 0.0f;
        #pragma unroll
        for (int r = 0; r < TR; ++r) {
            float acc = jb;
            #pragma unroll
            for (int k = 0; k < K; ++k)
                acc = fmaf(rows[r * NC + ji[k]], jw[k], acc);
            const float u = RELU ? fmaxf(acc, 0.0f) : gelu_exact(acc);
            out[(row0 + r) * NC + j] = u;            // coalesced across lanes
            if (STATS) { s1 += u; s2 = fmaf(u, u, s2); }
        }
        if (STATS) {
            const int rep = blockIdx.x & (NREP - 1);
            atomicAdd(&ssum[rep * NC + j], s1);
            atomicAdd(&ssq[rep * NC + j],  s2);
        }
    }
}

// Finalize BN stats AND fold the resulting affine into the NEXT layer's weights:
//   in'[c] = in[c]*sc[c] + sh[c]
//   sum_k in'[c_k]*W[j,k] + b[j] = sum_k in[c_k]*(W[j,k]*sc[c_k]) + (b[j] + sum_k sh[c_k]*W[j,k])
// Single block, 1024 threads.
template<int K>
__global__ void bn_fold(const float* __restrict__ sum,    // NREP*NC
                        const float* __restrict__ sumsq,  // NREP*NC
                        const float* __restrict__ gamma,
                        const float* __restrict__ beta,
                        const int*   __restrict__ nidx,   // next layer idx  [NC,K]
                        const float* __restrict__ nW,     // next layer W    [NC,K]
                        const float* __restrict__ nb,     // next layer bias [NC]
                        float*       __restrict__ Wf,     // folded W        [NC,K]
                        float*       __restrict__ bf)     // folded bias     [NC]
{
    __shared__ float s_sc[NC], s_sh[NC];
    const int j = threadIdx.x;
    if (j < NC) {
        float s1 = 0.0f, s2 = 0.0f;
        #pragma unroll
        for (int r = 0; r < NREP; ++r) { s1 += sum[r * NC + j]; s2 += sumsq[r * NC + j]; }
        const float invB = 1.0f / (float)BROWS;
        const float m    = s1 * invB;
        const float var  = fmaf(-m, m, s2 * invB);
        const float sc   = gamma[j] * rsqrtf(var + EPS);
        s_sc[j] = sc;
        s_sh[j] = fmaf(-m, sc, beta[j]);
    }
    __syncthreads();
    if (j < NC) {
        float acc = nb[j];
        #pragma unroll
        for (int k = 0; k < K; ++k) {
            const int   c = nidx[j * K + k];
            const float w = nW[j * K + k];
            Wf[j * K + k] = w * s_sc[c];
            acc = fmaf(w, s_sh[c], acc);
        }
        bf[j] = acc;
    }
}

extern "C" void kernel_launch(void* const* d_in, const int* in_sizes, int n_in,
                              void* d_out, int out_size, void* d_ws, size_t ws_size,
                              hipStream_t stream)
{
    const float* x    = (const float*)d_in[0];
    const int*   idx1 = (const int*)  d_in[1];
    const float* W1   = (const float*)d_in[2];
    const float* b1   = (const float*)d_in[3];
    const int*   idx2 = (const int*)  d_in[4];
    const float* W2   = (const float*)d_in[5];
    const float* b2   = (const float*)d_in[6];
    const int*   idx3 = (const int*)  d_in[7];
    const float* W3   = (const float*)d_in[8];
    const float* b3   = (const float*)d_in[9];
    const float* g2   = (const float*)d_in[10];
    const float* be2  = (const float*)d_in[11];
    const float* g3   = (const float*)d_in[12];
    const float* be3  = (const float*)d_in[13];
    float* out = (float*)d_out;

    const size_t BN_ELEMS = (size_t)BROWS * NC;
    // Ping-pong: L1 w:A(out), L2 r:A w:B, L3 r:B w:A, L4 r:A w:B, L5 r:B w:out. No alias.
    float* bufA = out;
    float* bufB = (float*)d_ws;
    float* p    = bufB + BN_ELEMS;
    float* sum2a = p; p += NREP*NC;  float* ssq2a = p; p += NREP*NC;
    float* sum3  = p; p += NREP*NC;  float* ssq3  = p; p += NREP*NC;
    float* sum2b = p; p += NREP*NC;  float* ssq2b = p; p += NREP*NC;
    float* W3f   = p; p += (size_t)NC*8;  float* b3f = p; p += NC;
    float* W2f   = p; p += (size_t)NC*4;  float* b2f = p; p += NC;
    float* W1f   = p; p += (size_t)NC*2;  float* b1f = p; p += NC;

    // ws is poisoned 0xAA before every call: zero the atomic accumulators.
    hipMemsetAsync(sum2a, 0, 6 * NREP * NC * sizeof(float), stream);

    const dim3 grid(BROWS / TR), blk(THREADS);

    // L1: h1 = gelu(sp1(x))                         -> bufA
    sparse_layer<2,false,false><<<grid, blk, 0, stream>>>(
        x, idx1, W1, b1, bufA, nullptr, nullptr);
    // L2: u2 = gelu(sp2(h1)), bn2a stats            -> bufB
    sparse_layer<4,true,false><<<grid, blk, 0, stream>>>(
        bufA, idx2, W2, b2, bufB, sum2a, ssq2a);
    bn_fold<8><<<1, 1024, 0, stream>>>(sum2a, ssq2a, g2, be2, idx3, W3, b3, W3f, b3f);
    // L3: u3 = gelu(sp3(bn2a(u2))) via folded W3    -> bufA
    sparse_layer<8,true,false><<<grid, blk, 0, stream>>>(
        bufB, idx3, W3f, b3f, bufA, sum3, ssq3);
    bn_fold<4><<<1, 1024, 0, stream>>>(sum3, ssq3, g3, be3, idx2, W2, b2, W2f, b2f);
    // L4: u4 = gelu(sp2(bn3(u3))) via folded W2     -> bufB
    sparse_layer<4,true,false><<<grid, blk, 0, stream>>>(
        bufA, idx2, W2f, b2f, bufB, sum2b, ssq2b);
    bn_fold<2><<<1, 1024, 0, stream>>>(sum2b, ssq2b, g2, be2, idx1, W1, b1, W1f, b1f);
    // L5: out = relu(sp1(bn2b(u4))) via folded W1   -> d_out
    sparse_layer<2,false,true><<<grid, blk, 0, stream>>>(
        bufB, idx1, W1f, b1f, out, nullptr, nullptr);
}